// Round 4
// baseline (1444.354 us; speedup 1.0000x reference)
//
#include <hip/hip_runtime.h>
#include <hip/hip_bf16.h>
#include <math.h>

// Problem constants
#define BB 2
#define SS 2048
#define DDIM 1024
#define NHEAD 16
#define HDIMC 64
#define NSTR 8
#define SDIMC 128
#define NCH 16      // chunks for delta scan
#define CLEN 128    // chunk length
#define EPSV 1e-6f

using bf16 = __hip_bfloat16;
typedef __attribute__((ext_vector_type(8))) __bf16 bf8;
typedef __attribute__((ext_vector_type(4))) float f4;

__device__ __forceinline__ bf16 f2b(float v) { return __float2bfloat16(v); }
__device__ __forceinline__ bf8 ld8(const bf16* p) { return *(const bf8*)p; }
__device__ __forceinline__ f4 MFMA(bf8 a, bf8 b, f4 c) {
  return __builtin_amdgcn_mfma_f32_16x16x32_bf16(a, b, c, 0, 0, 0);
}
__device__ __forceinline__ float sigm(float x) { return 1.0f / (1.0f + expf(-x)); }

// ---------------- f32 -> bf16 weight conversion ----------------
__global__ __launch_bounds__(256) void cvt_k(const float* __restrict__ in,
                                             bf16* __restrict__ out, int n) {
  int i = blockIdx.x * 256 + threadIdx.x;
  if (i < n) out[i] = f2b(in[i]);
}

// ---------------- Delta operator: 3-pass chunked affine scan ----------------
__global__ __launch_bounds__(256) void delta_passA(const float* __restrict__ x,
                                                   const float* __restrict__ decay,
                                                   float* __restrict__ SA) {
  int idx = blockIdx.x * 256 + threadIdx.x;      // [b][c][d]
  int d = idx % DDIM;
  int c = (idx / DDIM) % NCH;
  int b = idx / (DDIM * NCH);
  float beta = sigm(decay[d]);
  float omb = 1.0f - beta;
  const float* xp = x + ((size_t)(b * SS + c * CLEN)) * DDIM + d;
  float s = 0.0f;
  for (int j = 0; j < CLEN; j++) {
    float xv = xp[(size_t)j * DDIM];
    s = beta * s + omb * xv;
  }
  SA[idx] = s;
}

__global__ __launch_bounds__(256) void delta_passB(const float* __restrict__ SA,
                                                   const float* __restrict__ decay,
                                                   float* __restrict__ SIN) {
  int idx = blockIdx.x * 256 + threadIdx.x;      // [b][d]
  int d = idx % DDIM;
  int b = idx / DDIM;
  float beta = sigm(decay[d]);
  float p = beta;
  for (int i = 0; i < 7; i++) p *= p;            // beta^128
  float s = 0.0f;
  for (int c = 0; c < NCH; c++) {
    SIN[(b * NCH + c) * DDIM + d] = s;
    s = p * s + SA[(b * NCH + c) * DDIM + d];
  }
}

__global__ __launch_bounds__(256) void delta_passC(const float* __restrict__ x,
                                                   const float* __restrict__ decay,
                                                   const float* __restrict__ SIN,
                                                   float* __restrict__ XD,
                                                   float* __restrict__ SA) {
  int idx = blockIdx.x * 256 + threadIdx.x;      // [b][c][d]
  int d = idx % DDIM;
  int c = (idx / DDIM) % NCH;
  int b = idx / (DDIM * NCH);
  float beta = sigm(decay[d]);
  float omb = 1.0f - beta;
  const float* xp = x + ((size_t)(b * SS + c * CLEN)) * DDIM + d;
  float* xdp = XD + ((size_t)(b * SS + c * CLEN)) * DDIM + d;
  float s = SIN[idx];
  float sum = 0.0f;
  for (int j = 0; j < CLEN; j++) {
    float xv = xp[(size_t)j * DDIM];
    float o = xv - s;
    xdp[(size_t)j * DDIM] = o;
    sum += o;
    s = beta * s + omb * xv;
  }
  SA[idx] = sum;
}

// ---------------- gates (g_res) + sinkhorn ----------------
__global__ __launch_bounds__(1024) void gates_sinkhorn(const float* __restrict__ SA,
                                                       const float* __restrict__ gw,
                                                       const float* __restrict__ gb,
                                                       const float* __restrict__ phi,
                                                       float* __restrict__ gres,
                                                       float* __restrict__ hres) {
  int tid = threadIdx.x;
  int wave = tid >> 6, lane = tid & 63;
  int b = wave >> 3, j = wave & 7;               // 16 waves: (b, gate j)
  float acc = 0.0f;
  for (int d = lane; d < DDIM; d += 64) {
    float xs = 0.0f;
    for (int c = 0; c < NCH; c++) xs += SA[(b * NCH + c) * DDIM + d];
    xs *= (1.0f / (float)SS);
    acc += xs * gw[(2 * NSTR + j) * DDIM + d];
  }
  for (int off = 32; off > 0; off >>= 1) acc += __shfl_down(acc, off);
  if (lane == 0) gres[b * NSTR + j] = sigm(acc + gb[2 * NSTR + j]);
  __syncthreads();
  if (tid == 0) {
    float Km[8][8];
    for (int i = 0; i < 8; i++)
      for (int jj = 0; jj < 8; jj++) Km[i][jj] = expf(phi[i * 8 + jj]);
    for (int it = 0; it < 15; it++) {
      for (int i = 0; i < 8; i++) {
        float rs = 0.0f;
        for (int jj = 0; jj < 8; jj++) rs += Km[i][jj];
        float inv = 1.0f / rs;
        for (int jj = 0; jj < 8; jj++) Km[i][jj] *= inv;
      }
      for (int jj = 0; jj < 8; jj++) {
        float cs = 0.0f;
        for (int i = 0; i < 8; i++) cs += Km[i][jj];
        float inv = 1.0f / cs;
        for (int i = 0; i < 8; i++) Km[i][jj] *= inv;
      }
    }
    for (int i = 0; i < 8; i++)
      for (int jj = 0; jj < 8; jj++) hres[i * 8 + jj] = Km[i][jj];
  }
}

// ---------------- RMSNorm (f32 in -> bf16 out) ----------------
__global__ __launch_bounds__(256) void rmsnorm_k(const float* __restrict__ in,
                                                 const float* __restrict__ w,
                                                 bf16* __restrict__ out) {
  int row = blockIdx.x;
  const float* r = in + (size_t)row * DDIM;
  int tid = threadIdx.x;
  float ss = 0.0f;
  for (int i = tid; i < DDIM; i += 256) {
    float v = r[i];
    ss += v * v;
  }
  for (int off = 32; off > 0; off >>= 1) ss += __shfl_down(ss, off);
  __shared__ float red[4];
  if ((tid & 63) == 0) red[tid >> 6] = ss;
  __syncthreads();
  float tot = red[0] + red[1] + red[2] + red[3];
  float sc = rsqrtf(tot / (float)DDIM + EPSV);
  bf16* o = out + (size_t)row * DDIM;
  for (int i = tid; i < DDIM; i += 256) o[i] = f2b(r[i] * sc * w[i]);
}

// ---------------- MFMA GEMM: C[M,N] = A[M,K] @ W[N,K]^T + bias (+epi) -------
// ODT: 0=f32 out, 1=bf16 out.  EPI: 0=none, 1=gelu, 2=add residual (f32)
template <int ODT, int EPI>
__global__ __launch_bounds__(256) void gemm_bt(const bf16* __restrict__ A,
                                               const bf16* __restrict__ W,
                                               const float* __restrict__ bias,
                                               const float* __restrict__ res,
                                               void* __restrict__ outp,
                                               int M, int N, int K) {
  int lane = threadIdx.x & 63, wv = threadIdx.x >> 6;
  int ml = lane & 15, quad = lane >> 4;
  int m0 = blockIdx.x * 64 + wv * 16;
  int n0 = blockIdx.y * 64;
  f4 acc[4] = {{0,0,0,0},{0,0,0,0},{0,0,0,0},{0,0,0,0}};
  const bf16* arow = A + (size_t)(m0 + ml) * K + quad * 8;
  for (int k0 = 0; k0 < K; k0 += 32) {
    bf8 af = ld8(arow + k0);
#pragma unroll
    for (int c = 0; c < 4; c++) {
      bf8 bfr = ld8(W + (size_t)(n0 + c * 16 + ml) * K + k0 + quad * 8);
      acc[c] = MFMA(af, bfr, acc[c]);
    }
  }
#pragma unroll
  for (int c = 0; c < 4; c++) {
#pragma unroll
    for (int r = 0; r < 4; r++) {
      int row = m0 + quad * 4 + r;
      int col = n0 + c * 16 + ml;
      size_t idx = (size_t)row * N + col;
      float v = acc[c][r] + bias[col];
      if (EPI == 1) v = 0.5f * v * (1.0f + erff(v * 0.70710678118654752f));
      if (EPI == 2) v += res[idx];
      if (ODT == 1) ((bf16*)outp)[idx] = f2b(v);
      else ((float*)outp)[idx] = v;
    }
  }
}

// ---------------- V transpose: VT[b,h,d,s] = qkv[b,s,2D + h*64 + d] --------
__global__ __launch_bounds__(256) void vtrans(const bf16* __restrict__ qkv,
                                              bf16* __restrict__ VT) {
  int bid = blockIdx.x;
  int st = bid % (SS / 64);
  int h = (bid / (SS / 64)) % NHEAD;
  int b = bid / ((SS / 64) * NHEAD);
  __shared__ bf16 tile[64][65];
  int s0 = st * 64;
  int tid = threadIdx.x;
  for (int it = 0; it < 16; it++) {
    int sl = it * 4 + (tid >> 6), dl = tid & 63;
    tile[sl][dl] = qkv[(size_t)(b * SS + s0 + sl) * (3 * DDIM) + 2 * DDIM + h * 64 + dl];
  }
  __syncthreads();
  for (int it = 0; it < 16; it++) {
    int dl = it * 4 + (tid >> 6), sl = tid & 63;
    VT[((size_t)(b * NHEAD + h) * 64 + dl) * SS + s0 + sl] = tile[sl][dl];
  }
}

// ---------------- Flash attention (causal, 16 heads, hd=64) ----------------
__global__ __launch_bounds__(256) void flash_attn(const bf16* __restrict__ qkv,
                                                  const bf16* __restrict__ VT,
                                                  bf16* __restrict__ obuf) {
  int bid = blockIdx.x;
  int qt = bid % (SS / 64);
  int h = (bid / (SS / 64)) % NHEAD;
  int b = bid / ((SS / 64) * NHEAD);
  int wv = threadIdx.x >> 6, lane = threadIdx.x & 63;
  int ml = lane & 15, quad = lane >> 4;
  int q0 = qt * 64;
  int qrow = q0 + wv * 16 + ml;

  // Q fragment from the Q section of the QKV projection (offset 0, stride 3D)
  bf8 qf[2];
#pragma unroll
  for (int kk = 0; kk < 2; kk++)
    qf[kk] = ld8(qkv + (size_t)(b * SS + qrow) * (3 * DDIM) + h * 64 + kk * 32 + quad * 8);

  f4 oacc[4] = {{0,0,0,0},{0,0,0,0},{0,0,0,0},{0,0,0,0}};
  float m_r[4], l_r[4];
#pragma unroll
  for (int r = 0; r < 4; r++) { m_r[r] = -1e30f; l_r[r] = 0.0f; }

  __shared__ __align__(16) bf16 plds[4][16][64];
  int nkt = qt + 1;
  for (int kt = 0; kt < nkt; kt++) {
    int k0 = kt * 64;
    f4 sacc[4] = {{0,0,0,0},{0,0,0,0},{0,0,0,0},{0,0,0,0}};
#pragma unroll
    for (int kk = 0; kk < 2; kk++) {
#pragma unroll
      for (int c = 0; c < 4; c++) {
        bf8 kf = ld8(qkv + (size_t)(b * SS + k0 + c * 16 + ml) * (3 * DDIM) + DDIM +
                     h * 64 + kk * 32 + quad * 8);
        sacc[c] = MFMA(qf[kk], kf, sacc[c]);
      }
    }
    float sv[4][4];
#pragma unroll
    for (int c = 0; c < 4; c++)
#pragma unroll
      for (int r = 0; r < 4; r++) {
        int qi = q0 + wv * 16 + quad * 4 + r;
        int kj = k0 + c * 16 + ml;
        float v = sacc[c][r] * 0.125f;  // 1/sqrt(64)
        sv[c][r] = (kj <= qi) ? v : -1e9f;
      }
    float alpha[4];
#pragma unroll
    for (int r = 0; r < 4; r++) {
      float mx = fmaxf(fmaxf(sv[0][r], sv[1][r]), fmaxf(sv[2][r], sv[3][r]));
      for (int off = 1; off < 16; off <<= 1) mx = fmaxf(mx, __shfl_xor(mx, off));
      float mn = fmaxf(m_r[r], mx);
      float rs = 0.0f;
#pragma unroll
      for (int c = 0; c < 4; c++) {
        float p = expf(sv[c][r] - mn);
        sv[c][r] = p;
        rs += p;
      }
      for (int off = 1; off < 16; off <<= 1) rs += __shfl_xor(rs, off);
      alpha[r] = expf(m_r[r] - mn);
      l_r[r] = l_r[r] * alpha[r] + rs;
      m_r[r] = mn;
    }
#pragma unroll
    for (int c = 0; c < 4; c++)
#pragma unroll
      for (int r = 0; r < 4; r++) oacc[c][r] *= alpha[r];
    __syncthreads();  // protect plds reuse across iterations
#pragma unroll
    for (int c = 0; c < 4; c++)
#pragma unroll
      for (int r = 0; r < 4; r++)
        plds[wv][quad * 4 + r][c * 16 + ml] = f2b(sv[c][r]);
    __syncthreads();
    bf8 pf[2];
#pragma unroll
    for (int kk = 0; kk < 2; kk++) pf[kk] = ld8(&plds[wv][ml][kk * 32 + quad * 8]);
#pragma unroll
    for (int c = 0; c < 4; c++) {
#pragma unroll
      for (int kk = 0; kk < 2; kk++) {
        bf8 vf = ld8(VT + ((size_t)(b * NHEAD + h) * 64 + c * 16 + ml) * SS + k0 +
                     kk * 32 + quad * 8);
        oacc[c] = MFMA(pf[kk], vf, oacc[c]);
      }
    }
  }
#pragma unroll
  for (int c = 0; c < 4; c++)
#pragma unroll
    for (int r = 0; r < 4; r++) {
      int row = q0 + wv * 16 + quad * 4 + r;
      obuf[(size_t)(b * SS + row) * DDIM + h * 64 + c * 16 + ml] =
          f2b(oacc[c][r] / l_r[r]);
    }
}

// ---------------- final: out = (y+ffn) + mhc ----------------
__global__ __launch_bounds__(256) void final_k(const float* __restrict__ yffn,
                                               const float* __restrict__ xd,
                                               const float* __restrict__ hres,
                                               const float* __restrict__ gres,
                                               float* __restrict__ out) {
  int row = blockIdx.x;  // [B*S]
  int b = row / SS;
  int tid = threadIdx.x;
  __shared__ float cf[8][8];
  if (tid < 64) cf[tid >> 3][tid & 7] = hres[tid] * gres[b * NSTR + (tid & 7)];
  __syncthreads();
  const float* yr = yffn + (size_t)row * DDIM;
  const float* xr = xd + (size_t)row * DDIM;
  float* o = out + (size_t)row * DDIM;
  for (int i = tid; i < DDIM; i += 256) {
    int m = i >> 7, dd = i & 127;
    float acc = yr[i];
#pragma unroll
    for (int n = 0; n < 8; n++) acc += cf[m][n] * xr[n * SDIMC + dd];
    o[i] = acc;
  }
}

extern "C" void kernel_launch(void* const* d_in, const int* in_sizes, int n_in,
                              void* d_out, int out_size, void* d_ws, size_t ws_size,
                              hipStream_t stream) {
  // ALL inputs are float32 per the reference setup_inputs (jnp.float32)
  const float* x     = (const float*)d_in[0];
  const float* decay = (const float*)d_in[3];
  const float* gw    = (const float*)d_in[4];
  const float* gb    = (const float*)d_in[5];
  const float* phi   = (const float*)d_in[6];
  const float* ln1   = (const float*)d_in[7];
  const float* ln2   = (const float*)d_in[8];
  const float* w1    = (const float*)d_in[9];
  const float* b1    = (const float*)d_in[10];
  const float* w2    = (const float*)d_in[11];
  const float* b2    = (const float*)d_in[12];
  const float* ipw   = (const float*)d_in[13];
  const float* ipb   = (const float*)d_in[14];
  const float* ow    = (const float*)d_in[15];
  const float* obs   = (const float*)d_in[16];
  float* out = (float*)d_out;

  // ---- workspace layout (105 MB total) ----
  const size_t MB = 1048576ull;
  char* wsp = (char*)d_ws;
  float* SA   = (float*)(wsp);                 // 128 KB  chunk states / sums
  float* SIN  = (float*)(wsp + 131072ull);     // 128 KB  incoming states
  float* GRES = (float*)(wsp + 262144ull);     // 64 B
  float* HRES = (float*)(wsp + 262208ull);     // 256 B
  float* XD   = (float*)(wsp + 1 * MB);        // 16 MB   x_delta (f32)
  float* AO   = (float*)(wsp + 17 * MB);       // 16 MB   y = x_delta+attn; then +ffn (in-place)
  bf16*  NORM = (bf16*)(wsp + 33 * MB);        // 8 MB    normed / normed2 (bf16)
  bf16*  OB   = (bf16*)(wsp + 41 * MB);        // 8 MB    attn heads out (bf16)
  bf16*  QKV  = (bf16*)(wsp + 49 * MB);        // 24 MB   (dead after flash)
  bf16*  VT   = (bf16*)(wsp + 73 * MB);        // 8 MB    (dead after flash)
  bf16*  HB   = (bf16*)(wsp + 49 * MB);        // 32 MB   gelu hidden, ALIASES QKV+VT
  float* FFN  = (float*)(wsp + 17 * MB);       // in-place over AO (same-thread RMW)
  bf16*  WIPW = (bf16*)(wsp + 81 * MB);        // 6 MB    in_proj_w bf16
  bf16*  WOW  = (bf16*)(wsp + 87 * MB);        // 2 MB    out_w bf16
  bf16*  W1B  = (bf16*)(wsp + 89 * MB);        // 8 MB    w1 bf16
  bf16*  W2B  = (bf16*)(wsp + 97 * MB);        // 8 MB    w2 bf16

  // 0: convert GEMM weights f32 -> bf16
  cvt_k<<<dim3((3 * DDIM * DDIM + 255) / 256), dim3(256), 0, stream>>>(ipw, WIPW, 3 * DDIM * DDIM);
  cvt_k<<<dim3((DDIM * DDIM + 255) / 256), dim3(256), 0, stream>>>(ow, WOW, DDIM * DDIM);
  cvt_k<<<dim3((4 * DDIM * DDIM + 255) / 256), dim3(256), 0, stream>>>(w1, W1B, 4 * DDIM * DDIM);
  cvt_k<<<dim3((4 * DDIM * DDIM + 255) / 256), dim3(256), 0, stream>>>(w2, W2B, 4 * DDIM * DDIM);

  // 1-3: delta operator scan
  delta_passA<<<dim3(BB * NCH * DDIM / 256), dim3(256), 0, stream>>>(x, decay, SA);
  delta_passB<<<dim3(BB * DDIM / 256), dim3(256), 0, stream>>>(SA, decay, SIN);
  delta_passC<<<dim3(BB * NCH * DDIM / 256), dim3(256), 0, stream>>>(x, decay, SIN, XD, SA);
  // 4: gates + sinkhorn
  gates_sinkhorn<<<dim3(1), dim3(1024), 0, stream>>>(SA, gw, gb, phi, GRES, HRES);
  // 5: rmsnorm1 (XD -> NORM)
  rmsnorm_k<<<dim3(BB * SS), dim3(256), 0, stream>>>(XD, ln1, NORM);
  // 6: qkv = NORM @ in_proj_w.T + in_proj_b   [4096 x 3072]
  gemm_bt<1, 0><<<dim3(64, 48), dim3(256), 0, stream>>>(NORM, WIPW, ipb, nullptr,
                                                        QKV, BB * SS, 3 * DDIM, DDIM);
  // 7: V transpose
  vtrans<<<dim3(BB * NHEAD * (SS / 64)), dim3(256), 0, stream>>>(QKV, VT);
  // 8: flash attention -> OB  (Q now read from QKV section 0)
  flash_attn<<<dim3(BB * NHEAD * (SS / 64)), dim3(256), 0, stream>>>(QKV, VT, OB);
  // 9: out-proj + residual(XD) -> AO (= y = x_delta + attn_out)
  gemm_bt<0, 2><<<dim3(64, 16), dim3(256), 0, stream>>>(OB, WOW, obs, XD,
                                                        AO, BB * SS, DDIM, DDIM);
  // 10: rmsnorm2 (AO -> NORM)
  rmsnorm_k<<<dim3(BB * SS), dim3(256), 0, stream>>>(AO, ln2, NORM);
  // 11: ffn1 + gelu -> HB   [4096 x 4096]  (HB aliases dead QKV/VT)
  gemm_bt<1, 1><<<dim3(64, 64), dim3(256), 0, stream>>>(NORM, W1B, b1, nullptr,
                                                        HB, BB * SS, 4 * DDIM, DDIM);
  // 12: ffn2 + residual(AO=y) -> FFN (in-place over AO; same thread reads+writes)
  gemm_bt<0, 2><<<dim3(64, 16), dim3(256), 0, stream>>>(HB, W2B, b2, AO,
                                                        FFN, BB * SS, DDIM, 4 * DDIM);
  // 13: final out = FFN + mhc(XD)
  final_k<<<dim3(BB * SS), dim3(256), 0, stream>>>(FFN, XD, HRES, GRES, out);
}

// Round 5
// 670.141 us; speedup vs baseline: 2.1553x; 2.1553x over previous
//
#include <hip/hip_runtime.h>
#include <hip/hip_bf16.h>
#include <math.h>

// Problem constants
#define BB 2
#define SS 2048
#define DDIM 1024
#define NHEAD 16
#define NSTR 8
#define SDIMC 128
#define NCH 16      // chunks for delta scan
#define CLEN 128    // chunk length
#define EPSV 1e-6f

using bf16 = __hip_bfloat16;
typedef __attribute__((ext_vector_type(8))) __bf16 bf8;
typedef __attribute__((ext_vector_type(4))) float f4;

__device__ __forceinline__ bf16 f2b(float v) { return __float2bfloat16(v); }
__device__ __forceinline__ bf8 ld8(const bf16* p) { return *(const bf8*)p; }
__device__ __forceinline__ f4 MFMA(bf8 a, bf8 b, f4 c) {
  return __builtin_amdgcn_mfma_f32_16x16x32_bf16(a, b, c, 0, 0, 0);
}
__device__ __forceinline__ float sigm(float x) { return 1.0f / (1.0f + expf(-x)); }
__device__ __forceinline__ float fexp2(float x) { return __builtin_amdgcn_exp2f(x); }

// async global->LDS 16B copy (m97 pattern; LDS dest must be uniform + lane*16)
__device__ __forceinline__ void glds16(bf16* l, const bf16* g) {
  __builtin_amdgcn_global_load_lds(
      (const __attribute__((address_space(1))) unsigned int*)g,
      (__attribute__((address_space(3))) unsigned int*)l, 16, 0, 0);
}

// ---------------- f32 -> bf16 weight conversion ----------------
__global__ __launch_bounds__(256) void cvt_k(const float* __restrict__ in,
                                             bf16* __restrict__ out, int n) {
  int i = blockIdx.x * 256 + threadIdx.x;
  if (i < n) out[i] = f2b(in[i]);
}

// ---------------- Delta operator: 3-pass chunked affine scan ----------------
__global__ __launch_bounds__(256) void delta_passA(const float* __restrict__ x,
                                                   const float* __restrict__ decay,
                                                   float* __restrict__ SA) {
  int idx = blockIdx.x * 256 + threadIdx.x;      // [b][c][d]
  int d = idx % DDIM;
  int c = (idx / DDIM) % NCH;
  int b = idx / (DDIM * NCH);
  float beta = sigm(decay[d]);
  float omb = 1.0f - beta;
  const float* xp = x + ((size_t)(b * SS + c * CLEN)) * DDIM + d;
  float s = 0.0f;
  for (int j = 0; j < CLEN; j++) {
    float xv = xp[(size_t)j * DDIM];
    s = beta * s + omb * xv;
  }
  SA[idx] = s;
}

__global__ __launch_bounds__(256) void delta_passB(const float* __restrict__ SA,
                                                   const float* __restrict__ decay,
                                                   float* __restrict__ SIN) {
  int idx = blockIdx.x * 256 + threadIdx.x;      // [b][d]
  int d = idx % DDIM;
  int b = idx / DDIM;
  float beta = sigm(decay[d]);
  float p = beta;
  for (int i = 0; i < 7; i++) p *= p;            // beta^128
  float s = 0.0f;
  for (int c = 0; c < NCH; c++) {
    SIN[(b * NCH + c) * DDIM + d] = s;
    s = p * s + SA[(b * NCH + c) * DDIM + d];
  }
}

__global__ __launch_bounds__(256) void delta_passC(const float* __restrict__ x,
                                                   const float* __restrict__ decay,
                                                   const float* __restrict__ SIN,
                                                   float* __restrict__ XD,
                                                   float* __restrict__ SA) {
  int idx = blockIdx.x * 256 + threadIdx.x;      // [b][c][d]
  int d = idx % DDIM;
  int c = (idx / DDIM) % NCH;
  int b = idx / (DDIM * NCH);
  float beta = sigm(decay[d]);
  float omb = 1.0f - beta;
  const float* xp = x + ((size_t)(b * SS + c * CLEN)) * DDIM + d;
  float* xdp = XD + ((size_t)(b * SS + c * CLEN)) * DDIM + d;
  float s = SIN[idx];
  float sum = 0.0f;
  for (int j = 0; j < CLEN; j++) {
    float xv = xp[(size_t)j * DDIM];
    float o = xv - s;
    xdp[(size_t)j * DDIM] = o;
    sum += o;
    s = beta * s + omb * xv;
  }
  SA[idx] = sum;
}

// ---------------- gates (g_res) + sinkhorn ----------------
__global__ __launch_bounds__(1024) void gates_sinkhorn(const float* __restrict__ SA,
                                                       const float* __restrict__ gw,
                                                       const float* __restrict__ gb,
                                                       const float* __restrict__ phi,
                                                       float* __restrict__ gres,
                                                       float* __restrict__ hres) {
  int tid = threadIdx.x;
  int wave = tid >> 6, lane = tid & 63;
  int b = wave >> 3, j = wave & 7;               // 16 waves: (b, gate j)
  float acc = 0.0f;
  for (int d = lane; d < DDIM; d += 64) {
    float xs = 0.0f;
    for (int c = 0; c < NCH; c++) xs += SA[(b * NCH + c) * DDIM + d];
    xs *= (1.0f / (float)SS);
    acc += xs * gw[(2 * NSTR + j) * DDIM + d];
  }
  for (int off = 32; off > 0; off >>= 1) acc += __shfl_down(acc, off);
  if (lane == 0) gres[b * NSTR + j] = sigm(acc + gb[2 * NSTR + j]);
  __syncthreads();
  if (tid == 0) {
    float Km[8][8];
    for (int i = 0; i < 8; i++)
      for (int jj = 0; jj < 8; jj++) Km[i][jj] = expf(phi[i * 8 + jj]);
    for (int it = 0; it < 15; it++) {
      for (int i = 0; i < 8; i++) {
        float rs = 0.0f;
        for (int jj = 0; jj < 8; jj++) rs += Km[i][jj];
        float inv = 1.0f / rs;
        for (int jj = 0; jj < 8; jj++) Km[i][jj] *= inv;
      }
      for (int jj = 0; jj < 8; jj++) {
        float cs = 0.0f;
        for (int i = 0; i < 8; i++) cs += Km[i][jj];
        float inv = 1.0f / cs;
        for (int i = 0; i < 8; i++) Km[i][jj] *= inv;
      }
    }
    for (int i = 0; i < 8; i++)
      for (int jj = 0; jj < 8; jj++) hres[i * 8 + jj] = Km[i][jj];
  }
}

// ---------------- RMSNorm (f32 in -> bf16 out) ----------------
__global__ __launch_bounds__(256) void rmsnorm_k(const float* __restrict__ in,
                                                 const float* __restrict__ w,
                                                 bf16* __restrict__ out) {
  int row = blockIdx.x;
  const float* r = in + (size_t)row * DDIM;
  int tid = threadIdx.x;
  float ss = 0.0f;
  for (int i = tid; i < DDIM; i += 256) {
    float v = r[i];
    ss += v * v;
  }
  for (int off = 32; off > 0; off >>= 1) ss += __shfl_down(ss, off);
  __shared__ float red[4];
  if ((tid & 63) == 0) red[tid >> 6] = ss;
  __syncthreads();
  float tot = red[0] + red[1] + red[2] + red[3];
  float sc = rsqrtf(tot / (float)DDIM + EPSV);
  bf16* o = out + (size_t)row * DDIM;
  for (int i = tid; i < DDIM; i += 256) o[i] = f2b(r[i] * sc * w[i]);
}

// ------- MFMA GEMM, m97 structure: 128x128 tile, BK=32, global_load_lds -----
// C[M,N] = A[M,K] @ W[N,K]^T + bias (+epi)
// ODT: 0=f32 out, 1=bf16 out.  EPI: 0=none, 1=gelu(exact erf), 2=add residual
template <int ODT, int EPI>
__global__ __launch_bounds__(256) void gemm_lds(const bf16* __restrict__ A,
                                                const bf16* __restrict__ W,
                                                const float* __restrict__ bias,
                                                const float* __restrict__ res,
                                                void* __restrict__ outp,
                                                int M, int N, int K) {
  __shared__ bf16 As[128 * 32];
  __shared__ bf16 Bs[128 * 32];
  int tid = threadIdx.x;
  int lane = tid & 63, wv = tid >> 6;
  int ml = lane & 15, quad = lane >> 4;
  int wr = wv >> 1, wc = wv & 1;
  int m0 = blockIdx.x * 128, n0 = blockIdx.y * 128;
  f4 acc[4][4] = {};
  for (int k0 = 0; k0 < K; k0 += 32) {
#pragma unroll
    for (int it = 0; it < 2; it++) {
      int c = it * 256 + tid;             // 512 16B-chunks per tile
      int row = c >> 2, kc = (c & 3) * 8;
      glds16(&As[c * 8], A + (size_t)(m0 + row) * K + k0 + kc);
      glds16(&Bs[c * 8], W + (size_t)(n0 + row) * K + k0 + kc);
    }
    __syncthreads();                      // drains vmcnt (incl. lds-loads)
    bf8 af[4], bfr[4];
#pragma unroll
    for (int mi = 0; mi < 4; mi++)
      af[mi] = ld8(&As[(wr * 64 + mi * 16 + ml) * 32 + quad * 8]);
#pragma unroll
    for (int ni = 0; ni < 4; ni++)
      bfr[ni] = ld8(&Bs[(wc * 64 + ni * 16 + ml) * 32 + quad * 8]);
#pragma unroll
    for (int mi = 0; mi < 4; mi++)
#pragma unroll
      for (int ni = 0; ni < 4; ni++)
        acc[mi][ni] = MFMA(af[mi], bfr[ni], acc[mi][ni]);
    __syncthreads();                      // protect LDS before next staging
  }
#pragma unroll
  for (int mi = 0; mi < 4; mi++)
#pragma unroll
    for (int ni = 0; ni < 4; ni++)
#pragma unroll
      for (int r = 0; r < 4; r++) {
        int row = m0 + wr * 64 + mi * 16 + quad * 4 + r;
        int col = n0 + wc * 64 + ni * 16 + ml;
        size_t idx = (size_t)row * N + col;
        float v = acc[mi][ni][r] + bias[col];
        if (EPI == 1) v = 0.5f * v * (1.0f + erff(v * 0.70710678118654752f));
        if (EPI == 2) v += res[idx];
        if (ODT == 1) ((bf16*)outp)[idx] = f2b(v);
        else ((float*)outp)[idx] = v;
      }
}

// ---------------- V transpose: VT[b,h,d,s] = qkv[b,s,2D + h*64 + d] --------
__global__ __launch_bounds__(256) void vtrans(const bf16* __restrict__ qkv,
                                              bf16* __restrict__ VT) {
  int bid = blockIdx.x;
  int st = bid % (SS / 64);
  int h = (bid / (SS / 64)) % NHEAD;
  int b = bid / ((SS / 64) * NHEAD);
  __shared__ bf16 tile[64][65];
  int s0 = st * 64;
  int tid = threadIdx.x;
  for (int it = 0; it < 16; it++) {
    int sl = it * 4 + (tid >> 6), dl = tid & 63;
    tile[sl][dl] = qkv[(size_t)(b * SS + s0 + sl) * (3 * DDIM) + 2 * DDIM + h * 64 + dl];
  }
  __syncthreads();
  for (int it = 0; it < 16; it++) {
    int dl = it * 4 + (tid >> 6), sl = tid & 63;
    VT[((size_t)(b * NHEAD + h) * 64 + dl) * SS + s0 + sl] = tile[sl][dl];
  }
}

// -------- Flash attention: 1 wave per block, 16 Q-rows, exp2 softmax --------
__global__ __launch_bounds__(64) void flash_attn(const bf16* __restrict__ qkv,
                                                 const bf16* __restrict__ VT,
                                                 bf16* __restrict__ obuf) {
  int bid = blockIdx.x;                 // [b][h][qs], qs = 16-row subtile
  int qs = bid & 127;
  int h = (bid >> 7) & 15;
  int b = bid >> 11;
  int lane = threadIdx.x;
  int ml = lane & 15, quad = lane >> 4;
  int q0 = qs * 16;
  const float SC = 0.125f * 1.44269504089f;   // 1/sqrt(64) * log2(e)

  bf8 qf[2];
#pragma unroll
  for (int kk = 0; kk < 2; kk++)
    qf[kk] = ld8(qkv + (size_t)(b * SS + q0 + ml) * (3 * DDIM) + h * 64 + kk * 32 + quad * 8);

  f4 oacc[4] = {{0,0,0,0},{0,0,0,0},{0,0,0,0},{0,0,0,0}};
  float m_r[4], l_r[4];
#pragma unroll
  for (int r = 0; r < 4; r++) { m_r[r] = -1e30f; l_r[r] = 0.0f; }

  __shared__ __align__(16) bf16 plds[16][64];  // per-wave private (1 wave/block)
  int nkt = (qs >> 2) + 1;
  for (int kt = 0; kt < nkt; kt++) {
    int k0 = kt * 64;
    f4 sacc[4] = {{0,0,0,0},{0,0,0,0},{0,0,0,0},{0,0,0,0}};
#pragma unroll
    for (int kk = 0; kk < 2; kk++) {
#pragma unroll
      for (int c = 0; c < 4; c++) {
        bf8 kf = ld8(qkv + (size_t)(b * SS + k0 + c * 16 + ml) * (3 * DDIM) + DDIM +
                     h * 64 + kk * 32 + quad * 8);
        sacc[c] = MFMA(qf[kk], kf, sacc[c]);
      }
    }
    float sv[4][4];
#pragma unroll
    for (int c = 0; c < 4; c++)
#pragma unroll
      for (int r = 0; r < 4; r++) sv[c][r] = sacc[c][r] * SC;
    if (kt == nkt - 1) {                 // only the diagonal tile needs masking
#pragma unroll
      for (int c = 0; c < 4; c++)
#pragma unroll
        for (int r = 0; r < 4; r++) {
          int qi = q0 + quad * 4 + r;
          int kj = k0 + c * 16 + ml;
          if (kj > qi) sv[c][r] = -1e9f;
        }
    }
    float alpha[4];
#pragma unroll
    for (int r = 0; r < 4; r++) {
      float mx = fmaxf(fmaxf(sv[0][r], sv[1][r]), fmaxf(sv[2][r], sv[3][r]));
      for (int off = 1; off < 16; off <<= 1) mx = fmaxf(mx, __shfl_xor(mx, off));
      float mn = fmaxf(m_r[r], mx);
      float rs = 0.0f;
#pragma unroll
      for (int c = 0; c < 4; c++) {
        float p = fexp2(sv[c][r] - mn);
        sv[c][r] = p;
        rs += p;
      }
      for (int off = 1; off < 16; off <<= 1) rs += __shfl_xor(rs, off);
      alpha[r] = fexp2(m_r[r] - mn);
      l_r[r] = l_r[r] * alpha[r] + rs;
      m_r[r] = mn;
    }
#pragma unroll
    for (int c = 0; c < 4; c++)
#pragma unroll
      for (int r = 0; r < 4; r++) oacc[c][r] *= alpha[r];
    // C-layout -> A-layout transform via per-wave LDS (no barriers: 1 wave)
#pragma unroll
    for (int c = 0; c < 4; c++)
#pragma unroll
      for (int r = 0; r < 4; r++)
        plds[quad * 4 + r][c * 16 + ml] = f2b(sv[c][r]);
    bf8 pf[2];
#pragma unroll
    for (int kk = 0; kk < 2; kk++) pf[kk] = ld8(&plds[ml][kk * 32 + quad * 8]);
#pragma unroll
    for (int c = 0; c < 4; c++) {
#pragma unroll
      for (int kk = 0; kk < 2; kk++) {
        bf8 vf = ld8(VT + ((size_t)(b * NHEAD + h) * 64 + c * 16 + ml) * SS + k0 +
                     kk * 32 + quad * 8);
        oacc[c] = MFMA(pf[kk], vf, oacc[c]);
      }
    }
  }
#pragma unroll
  for (int c = 0; c < 4; c++)
#pragma unroll
    for (int r = 0; r < 4; r++) {
      int row = q0 + quad * 4 + r;
      obuf[(size_t)(b * SS + row) * DDIM + h * 64 + c * 16 + ml] =
          f2b(oacc[c][r] / l_r[r]);
    }
}

// ---------------- final: out = (y+ffn) + mhc ----------------
__global__ __launch_bounds__(256) void final_k(const float* __restrict__ yffn,
                                               const float* __restrict__ xd,
                                               const float* __restrict__ hres,
                                               const float* __restrict__ gres,
                                               float* __restrict__ out) {
  int row = blockIdx.x;  // [B*S]
  int b = row / SS;
  int tid = threadIdx.x;
  __shared__ float cf[8][8];
  if (tid < 64) cf[tid >> 3][tid & 7] = hres[tid] * gres[b * NSTR + (tid & 7)];
  __syncthreads();
  const float* yr = yffn + (size_t)row * DDIM;
  const float* xr = xd + (size_t)row * DDIM;
  float* o = out + (size_t)row * DDIM;
  for (int i = tid; i < DDIM; i += 256) {
    int m = i >> 7, dd = i & 127;
    float acc = yr[i];
#pragma unroll
    for (int n = 0; n < 8; n++) acc += cf[m][n] * xr[n * SDIMC + dd];
    o[i] = acc;
  }
}

extern "C" void kernel_launch(void* const* d_in, const int* in_sizes, int n_in,
                              void* d_out, int out_size, void* d_ws, size_t ws_size,
                              hipStream_t stream) {
  const float* x     = (const float*)d_in[0];
  const float* decay = (const float*)d_in[3];
  const float* gw    = (const float*)d_in[4];
  const float* gb    = (const float*)d_in[5];
  const float* phi   = (const float*)d_in[6];
  const float* ln1   = (const float*)d_in[7];
  const float* ln2   = (const float*)d_in[8];
  const float* w1    = (const float*)d_in[9];
  const float* b1    = (const float*)d_in[10];
  const float* w2    = (const float*)d_in[11];
  const float* b2    = (const float*)d_in[12];
  const float* ipw   = (const float*)d_in[13];
  const float* ipb   = (const float*)d_in[14];
  const float* ow    = (const float*)d_in[15];
  const float* obs   = (const float*)d_in[16];
  float* out = (float*)d_out;

  // ---- workspace layout (105 MB total) ----
  const size_t MB = 1048576ull;
  char* wsp = (char*)d_ws;
  float* SA   = (float*)(wsp);                 // 128 KB  chunk states / sums
  float* SIN  = (float*)(wsp + 131072ull);     // 128 KB  incoming states
  float* GRES = (float*)(wsp + 262144ull);     // 64 B
  float* HRES = (float*)(wsp + 262208ull);     // 256 B
  float* XD   = (float*)(wsp + 1 * MB);        // 16 MB   x_delta (f32)
  float* AO   = (float*)(wsp + 17 * MB);       // 16 MB   y; then y+ffn in-place
  bf16*  NORM = (bf16*)(wsp + 33 * MB);        // 8 MB    normed / normed2 (bf16)
  bf16*  OB   = (bf16*)(wsp + 41 * MB);        // 8 MB    attn heads out (bf16)
  bf16*  QKV  = (bf16*)(wsp + 49 * MB);        // 24 MB   (dead after flash)
  bf16*  VT   = (bf16*)(wsp + 73 * MB);        // 8 MB    (dead after flash)
  bf16*  HB   = (bf16*)(wsp + 49 * MB);        // 32 MB   gelu hidden, ALIASES QKV+VT
  float* FFN  = (float*)(wsp + 17 * MB);       // in-place over AO (same-thread RMW)
  bf16*  WIPW = (bf16*)(wsp + 81 * MB);        // 6 MB    in_proj_w bf16
  bf16*  WOW  = (bf16*)(wsp + 87 * MB);        // 2 MB    out_w bf16
  bf16*  W1B  = (bf16*)(wsp + 89 * MB);        // 8 MB    w1 bf16
  bf16*  W2B  = (bf16*)(wsp + 97 * MB);        // 8 MB    w2 bf16

  // 0: convert GEMM weights f32 -> bf16
  cvt_k<<<dim3((3 * DDIM * DDIM + 255) / 256), dim3(256), 0, stream>>>(ipw, WIPW, 3 * DDIM * DDIM);
  cvt_k<<<dim3((DDIM * DDIM + 255) / 256), dim3(256), 0, stream>>>(ow, WOW, DDIM * DDIM);
  cvt_k<<<dim3((4 * DDIM * DDIM + 255) / 256), dim3(256), 0, stream>>>(w1, W1B, 4 * DDIM * DDIM);
  cvt_k<<<dim3((4 * DDIM * DDIM + 255) / 256), dim3(256), 0, stream>>>(w2, W2B, 4 * DDIM * DDIM);

  // 1-3: delta operator scan
  delta_passA<<<dim3(BB * NCH * DDIM / 256), dim3(256), 0, stream>>>(x, decay, SA);
  delta_passB<<<dim3(BB * DDIM / 256), dim3(256), 0, stream>>>(SA, decay, SIN);
  delta_passC<<<dim3(BB * NCH * DDIM / 256), dim3(256), 0, stream>>>(x, decay, SIN, XD, SA);
  // 4: gates + sinkhorn
  gates_sinkhorn<<<dim3(1), dim3(1024), 0, stream>>>(SA, gw, gb, phi, GRES, HRES);
  // 5: rmsnorm1 (XD -> NORM)
  rmsnorm_k<<<dim3(BB * SS), dim3(256), 0, stream>>>(XD, ln1, NORM);
  // 6: qkv = NORM @ in_proj_w.T + in_proj_b   [4096 x 3072]
  gemm_lds<1, 0><<<dim3(32, 24), dim3(256), 0, stream>>>(NORM, WIPW, ipb, nullptr,
                                                         QKV, BB * SS, 3 * DDIM, DDIM);
  // 7: V transpose
  vtrans<<<dim3(BB * NHEAD * (SS / 64)), dim3(256), 0, stream>>>(QKV, VT);
  // 8: flash attention -> OB   (1 wave / 16 Q-rows per block)
  flash_attn<<<dim3(BB * NHEAD * (SS / 16)), dim3(64), 0, stream>>>(QKV, VT, OB);
  // 9: out-proj + residual(XD) -> AO (= y = x_delta + attn_out)
  gemm_lds<0, 2><<<dim3(32, 8), dim3(256), 0, stream>>>(OB, WOW, obs, XD,
                                                        AO, BB * SS, DDIM, DDIM);
  // 10: rmsnorm2 (AO -> NORM)
  rmsnorm_k<<<dim3(BB * SS), dim3(256), 0, stream>>>(AO, ln2, NORM);
  // 11: ffn1 + gelu -> HB   [4096 x 4096]  (HB aliases dead QKV/VT)
  gemm_lds<1, 1><<<dim3(32, 32), dim3(256), 0, stream>>>(NORM, W1B, b1, nullptr,
                                                         HB, BB * SS, 4 * DDIM, DDIM);
  // 12: ffn2 + residual(AO=y) -> FFN (in-place over AO; same-thread RMW)
  gemm_lds<0, 2><<<dim3(32, 8), dim3(256), 0, stream>>>(HB, W2B, b2, AO,
                                                        FFN, BB * SS, DDIM, 4 * DDIM);
  // 13: final out = FFN + mhc(XD)
  final_k<<<dim3(BB * SS), dim3(256), 0, stream>>>(FFN, XD, HRES, GRES, out);
}

// Round 6
// 651.897 us; speedup vs baseline: 2.2156x; 1.0280x over previous
//
#include <hip/hip_runtime.h>
#include <hip/hip_bf16.h>
#include <math.h>

// Problem constants
#define BB 2
#define SS 2048
#define DDIM 1024
#define NHEAD 16
#define NSTR 8
#define SDIMC 128
#define NCH 16      // chunks for delta scan
#define CLEN 128    // chunk length
#define EPSV 1e-6f

using bf16 = __hip_bfloat16;
typedef __attribute__((ext_vector_type(8))) __bf16 bf8;
typedef __attribute__((ext_vector_type(4))) float f4;

__device__ __forceinline__ bf16 f2b(float v) { return __float2bfloat16(v); }
__device__ __forceinline__ bf8 ld8(const bf16* p) { return *(const bf8*)p; }
__device__ __forceinline__ f4 MFMA(bf8 a, bf8 b, f4 c) {
  return __builtin_amdgcn_mfma_f32_16x16x32_bf16(a, b, c, 0, 0, 0);
}
__device__ __forceinline__ float sigm(float x) { return 1.0f / (1.0f + expf(-x)); }
__device__ __forceinline__ float fexp2(float x) { return __builtin_amdgcn_exp2f(x); }

// async global->LDS 16B copy (m97 pattern; LDS dest must be uniform + lane*16)
__device__ __forceinline__ void glds16(bf16* l, const bf16* g) {
  __builtin_amdgcn_global_load_lds(
      (const __attribute__((address_space(1))) unsigned int*)g,
      (__attribute__((address_space(3))) unsigned int*)l, 16, 0, 0);
}

// ---------------- f32 -> bf16 weight conversion ----------------
__global__ __launch_bounds__(256) void cvt_k(const float* __restrict__ in,
                                             bf16* __restrict__ out, int n) {
  int i = blockIdx.x * 256 + threadIdx.x;
  if (i < n) out[i] = f2b(in[i]);
}

// ---------------- Delta operator: 3-pass chunked affine scan ----------------
__global__ __launch_bounds__(256) void delta_passA(const float* __restrict__ x,
                                                   const float* __restrict__ decay,
                                                   float* __restrict__ SA) {
  int idx = blockIdx.x * 256 + threadIdx.x;      // [b][c][d]
  int d = idx % DDIM;
  int c = (idx / DDIM) % NCH;
  int b = idx / (DDIM * NCH);
  float beta = sigm(decay[d]);
  float omb = 1.0f - beta;
  const float* xp = x + ((size_t)(b * SS + c * CLEN)) * DDIM + d;
  float s = 0.0f;
  for (int j = 0; j < CLEN; j++) {
    float xv = xp[(size_t)j * DDIM];
    s = beta * s + omb * xv;
  }
  SA[idx] = s;
}

__global__ __launch_bounds__(256) void delta_passB(const float* __restrict__ SA,
                                                   const float* __restrict__ decay,
                                                   float* __restrict__ SIN) {
  int idx = blockIdx.x * 256 + threadIdx.x;      // [b][d]
  int d = idx % DDIM;
  int b = idx / DDIM;
  float beta = sigm(decay[d]);
  float p = beta;
  for (int i = 0; i < 7; i++) p *= p;            // beta^128
  float s = 0.0f;
  for (int c = 0; c < NCH; c++) {
    SIN[(b * NCH + c) * DDIM + d] = s;
    s = p * s + SA[(b * NCH + c) * DDIM + d];
  }
}

__global__ __launch_bounds__(256) void delta_passC(const float* __restrict__ x,
                                                   const float* __restrict__ decay,
                                                   const float* __restrict__ SIN,
                                                   float* __restrict__ XD,
                                                   float* __restrict__ SA) {
  int idx = blockIdx.x * 256 + threadIdx.x;      // [b][c][d]
  int d = idx % DDIM;
  int c = (idx / DDIM) % NCH;
  int b = idx / (DDIM * NCH);
  float beta = sigm(decay[d]);
  float omb = 1.0f - beta;
  const float* xp = x + ((size_t)(b * SS + c * CLEN)) * DDIM + d;
  float* xdp = XD + ((size_t)(b * SS + c * CLEN)) * DDIM + d;
  float s = SIN[idx];
  float sum = 0.0f;
  for (int j = 0; j < CLEN; j++) {
    float xv = xp[(size_t)j * DDIM];
    float o = xv - s;
    xdp[(size_t)j * DDIM] = o;
    sum += o;
    s = beta * s + omb * xv;
  }
  SA[idx] = sum;
}

// ---------------- gates (g_res) + sinkhorn ----------------
__global__ __launch_bounds__(1024) void gates_sinkhorn(const float* __restrict__ SA,
                                                       const float* __restrict__ gw,
                                                       const float* __restrict__ gb,
                                                       const float* __restrict__ phi,
                                                       float* __restrict__ gres,
                                                       float* __restrict__ hres) {
  int tid = threadIdx.x;
  int wave = tid >> 6, lane = tid & 63;
  int b = wave >> 3, j = wave & 7;               // 16 waves: (b, gate j)
  float acc = 0.0f;
  for (int d = lane; d < DDIM; d += 64) {
    float xs = 0.0f;
    for (int c = 0; c < NCH; c++) xs += SA[(b * NCH + c) * DDIM + d];
    xs *= (1.0f / (float)SS);
    acc += xs * gw[(2 * NSTR + j) * DDIM + d];
  }
  for (int off = 32; off > 0; off >>= 1) acc += __shfl_down(acc, off);
  if (lane == 0) gres[b * NSTR + j] = sigm(acc + gb[2 * NSTR + j]);
  __syncthreads();
  if (tid == 0) {
    float Km[8][8];
    for (int i = 0; i < 8; i++)
      for (int jj = 0; jj < 8; jj++) Km[i][jj] = expf(phi[i * 8 + jj]);
    for (int it = 0; it < 15; it++) {
      for (int i = 0; i < 8; i++) {
        float rs = 0.0f;
        for (int jj = 0; jj < 8; jj++) rs += Km[i][jj];
        float inv = 1.0f / rs;
        for (int jj = 0; jj < 8; jj++) Km[i][jj] *= inv;
      }
      for (int jj = 0; jj < 8; jj++) {
        float cs = 0.0f;
        for (int i = 0; i < 8; i++) cs += Km[i][jj];
        float inv = 1.0f / cs;
        for (int i = 0; i < 8; i++) Km[i][jj] *= inv;
      }
    }
    for (int i = 0; i < 8; i++)
      for (int jj = 0; jj < 8; jj++) hres[i * 8 + jj] = Km[i][jj];
  }
}

// ---------------- RMSNorm (f32 in -> bf16 out) ----------------
__global__ __launch_bounds__(256) void rmsnorm_k(const float* __restrict__ in,
                                                 const float* __restrict__ w,
                                                 bf16* __restrict__ out) {
  int row = blockIdx.x;
  const float* r = in + (size_t)row * DDIM;
  int tid = threadIdx.x;
  float ss = 0.0f;
  for (int i = tid; i < DDIM; i += 256) {
    float v = r[i];
    ss += v * v;
  }
  for (int off = 32; off > 0; off >>= 1) ss += __shfl_down(ss, off);
  __shared__ float red[4];
  if ((tid & 63) == 0) red[tid >> 6] = ss;
  __syncthreads();
  float tot = red[0] + red[1] + red[2] + red[3];
  float sc = rsqrtf(tot / (float)DDIM + EPSV);
  bf16* o = out + (size_t)row * DDIM;
  for (int i = tid; i < DDIM; i += 256) o[i] = f2b(r[i] * sc * w[i]);
}

// ------- MFMA GEMM, m97 structure: 128x128 tile, BK=32, global_load_lds -----
// ODT: 0=f32 out, 1=bf16 out.  EPI: 0=none, 1=gelu(exact erf), 2=add residual
template <int ODT, int EPI>
__global__ __launch_bounds__(256) void gemm_lds(const bf16* __restrict__ A,
                                                const bf16* __restrict__ W,
                                                const float* __restrict__ bias,
                                                const float* __restrict__ res,
                                                void* __restrict__ outp,
                                                int M, int N, int K) {
  __shared__ bf16 As[128 * 32];
  __shared__ bf16 Bs[128 * 32];
  int tid = threadIdx.x;
  int lane = tid & 63, wv = tid >> 6;
  int ml = lane & 15, quad = lane >> 4;
  int wr = wv >> 1, wc = wv & 1;
  int m0 = blockIdx.x * 128, n0 = blockIdx.y * 128;
  f4 acc[4][4] = {};
  for (int k0 = 0; k0 < K; k0 += 32) {
#pragma unroll
    for (int it = 0; it < 2; it++) {
      int c = it * 256 + tid;             // 512 16B-chunks per tile
      int row = c >> 2, kc = (c & 3) * 8;
      glds16(&As[c * 8], A + (size_t)(m0 + row) * K + k0 + kc);
      glds16(&Bs[c * 8], W + (size_t)(n0 + row) * K + k0 + kc);
    }
    __syncthreads();
    bf8 af[4], bfr[4];
#pragma unroll
    for (int mi = 0; mi < 4; mi++)
      af[mi] = ld8(&As[(wr * 64 + mi * 16 + ml) * 32 + quad * 8]);
#pragma unroll
    for (int ni = 0; ni < 4; ni++)
      bfr[ni] = ld8(&Bs[(wc * 64 + ni * 16 + ml) * 32 + quad * 8]);
#pragma unroll
    for (int mi = 0; mi < 4; mi++)
#pragma unroll
      for (int ni = 0; ni < 4; ni++)
        acc[mi][ni] = MFMA(af[mi], bfr[ni], acc[mi][ni]);
    __syncthreads();
  }
#pragma unroll
  for (int mi = 0; mi < 4; mi++)
#pragma unroll
    for (int ni = 0; ni < 4; ni++)
#pragma unroll
      for (int r = 0; r < 4; r++) {
        int row = m0 + wr * 64 + mi * 16 + quad * 4 + r;
        int col = n0 + wc * 64 + ni * 16 + ml;
        size_t idx = (size_t)row * N + col;
        float v = acc[mi][ni][r] + bias[col];
        if (EPI == 1) v = 0.5f * v * (1.0f + erff(v * 0.70710678118654752f));
        if (EPI == 2) v += res[idx];
        if (ODT == 1) ((bf16*)outp)[idx] = f2b(v);
        else ((float*)outp)[idx] = v;
      }
}

// ------- MFMA GEMM, BM=64 x BN=128 variant (2 blocks/CU for N=1024 GEMMs) ---
template <int ODT, int EPI>
__global__ __launch_bounds__(256) void gemm_lds64(const bf16* __restrict__ A,
                                                  const bf16* __restrict__ W,
                                                  const float* __restrict__ bias,
                                                  const float* __restrict__ res,
                                                  void* __restrict__ outp,
                                                  int M, int N, int K) {
  __shared__ bf16 As[64 * 32];
  __shared__ bf16 Bs[128 * 32];
  int tid = threadIdx.x;
  int lane = tid & 63, wv = tid >> 6;
  int ml = lane & 15, quad = lane >> 4;
  int wr = wv & 1, wc = wv >> 1;        // wave tile: 32 rows x 64 cols
  int m0 = blockIdx.x * 64, n0 = blockIdx.y * 128;
  f4 acc[2][4] = {};
  for (int k0 = 0; k0 < K; k0 += 32) {
    {
      int c = tid;                      // A: 256 chunks
      int row = c >> 2, kc = (c & 3) * 8;
      glds16(&As[c * 8], A + (size_t)(m0 + row) * K + k0 + kc);
    }
#pragma unroll
    for (int it = 0; it < 2; it++) {    // B: 512 chunks
      int c = it * 256 + tid;
      int row = c >> 2, kc = (c & 3) * 8;
      glds16(&Bs[c * 8], W + (size_t)(n0 + row) * K + k0 + kc);
    }
    __syncthreads();
    bf8 af[2], bfr[4];
#pragma unroll
    for (int mi = 0; mi < 2; mi++)
      af[mi] = ld8(&As[(wr * 32 + mi * 16 + ml) * 32 + quad * 8]);
#pragma unroll
    for (int ni = 0; ni < 4; ni++)
      bfr[ni] = ld8(&Bs[(wc * 64 + ni * 16 + ml) * 32 + quad * 8]);
#pragma unroll
    for (int mi = 0; mi < 2; mi++)
#pragma unroll
      for (int ni = 0; ni < 4; ni++)
        acc[mi][ni] = MFMA(af[mi], bfr[ni], acc[mi][ni]);
    __syncthreads();
  }
#pragma unroll
  for (int mi = 0; mi < 2; mi++)
#pragma unroll
    for (int ni = 0; ni < 4; ni++)
#pragma unroll
      for (int r = 0; r < 4; r++) {
        int row = m0 + wr * 32 + mi * 16 + quad * 4 + r;
        int col = n0 + wc * 64 + ni * 16 + ml;
        size_t idx = (size_t)row * N + col;
        float v = acc[mi][ni][r] + bias[col];
        if (EPI == 1) v = 0.5f * v * (1.0f + erff(v * 0.70710678118654752f));
        if (EPI == 2) v += res[idx];
        if (ODT == 1) ((bf16*)outp)[idx] = f2b(v);
        else ((float*)outp)[idx] = v;
      }
}

// ---------------- V transpose: VT[b,h,d,s] = qkv[b,s,2D + h*64 + d] --------
__global__ __launch_bounds__(256) void vtrans(const bf16* __restrict__ qkv,
                                              bf16* __restrict__ VT) {
  int bid = blockIdx.x;
  int st = bid % (SS / 64);
  int h = (bid / (SS / 64)) % NHEAD;
  int b = bid / ((SS / 64) * NHEAD);
  __shared__ bf16 tile[64][65];
  int s0 = st * 64;
  int tid = threadIdx.x;
  for (int it = 0; it < 16; it++) {
    int sl = it * 4 + (tid >> 6), dl = tid & 63;
    tile[sl][dl] = qkv[(size_t)(b * SS + s0 + sl) * (3 * DDIM) + 2 * DDIM + h * 64 + dl];
  }
  __syncthreads();
  for (int it = 0; it < 16; it++) {
    int dl = it * 4 + (tid >> 6), sl = tid & 63;
    VT[((size_t)(b * NHEAD + h) * 64 + dl) * SS + s0 + sl] = tile[sl][dl];
  }
}

// ---- Flash attention: 4 independent waves/block (no barriers), V-early ----
// Wave wv of block handles Q subtile qs = qb*4+wv (16 rows); nkt = qb+1 is
// uniform across the block -> perfect balance. Heavy blocks launch first.
__global__ __launch_bounds__(256, 4) void flash_attn(const bf16* __restrict__ qkv,
                                                     const bf16* __restrict__ VT,
                                                     bf16* __restrict__ obuf) {
  int bid = blockIdx.x;                 // grid: BB*NHEAD*32
  int qb = 31 - (bid & 31);             // descending work order
  int h = (bid >> 5) & 15;
  int b = bid >> 9;
  int wv = threadIdx.x >> 6, lane = threadIdx.x & 63;
  int ml = lane & 15, quad = lane >> 4;
  int q0 = (qb * 4 + wv) * 16;
  const float SC = 0.125f * 1.44269504089f;   // 1/sqrt(64) * log2(e)

  __shared__ __align__(16) bf16 plds[4][16][64];
  bf16 (*pl)[64] = plds[wv];            // per-wave private slice, no barriers

  bf8 qf[2];
#pragma unroll
  for (int kk = 0; kk < 2; kk++)
    qf[kk] = ld8(qkv + (size_t)(b * SS + q0 + ml) * (3 * DDIM) + h * 64 + kk * 32 + quad * 8);

  f4 oacc[4] = {{0,0,0,0},{0,0,0,0},{0,0,0,0},{0,0,0,0}};
  float m_r[4], l_r[4];
#pragma unroll
  for (int r = 0; r < 4; r++) { m_r[r] = -1e30f; l_r[r] = 0.0f; }

  const bf16* kbase = qkv + (size_t)b * SS * (3 * DDIM) + DDIM + h * 64;
  const bf16* vbase = VT + (size_t)(b * NHEAD + h) * 64 * SS;
  int nkt = qb + 1;
  for (int kt = 0; kt < nkt; kt++) {
    int k0 = kt * 64;
    // issue K loads first, then V: QK waits vmcnt(8) (K only); softmax+LDS
    // transpose hide V latency; PV finds V resident.
    bf8 kf[8];
#pragma unroll
    for (int kk = 0; kk < 2; kk++)
#pragma unroll
      for (int c = 0; c < 4; c++)
        kf[kk * 4 + c] = ld8(kbase + (size_t)(k0 + c * 16 + ml) * (3 * DDIM) + kk * 32 + quad * 8);
    bf8 vf[8];
#pragma unroll
    for (int c = 0; c < 4; c++)
#pragma unroll
      for (int kk = 0; kk < 2; kk++)
        vf[c * 2 + kk] = ld8(vbase + (size_t)(c * 16 + ml) * SS + k0 + kk * 32 + quad * 8);
    f4 sacc[4] = {{0,0,0,0},{0,0,0,0},{0,0,0,0},{0,0,0,0}};
#pragma unroll
    for (int kk = 0; kk < 2; kk++)
#pragma unroll
      for (int c = 0; c < 4; c++)
        sacc[c] = MFMA(qf[kk], kf[kk * 4 + c], sacc[c]);
    float sv[4][4];
#pragma unroll
    for (int c = 0; c < 4; c++)
#pragma unroll
      for (int r = 0; r < 4; r++) sv[c][r] = sacc[c][r] * SC;
    if (kt == nkt - 1) {                // only the diagonal tile needs masking
#pragma unroll
      for (int c = 0; c < 4; c++)
#pragma unroll
        for (int r = 0; r < 4; r++) {
          int qi = q0 + quad * 4 + r;
          int kj = k0 + c * 16 + ml;
          if (kj > qi) sv[c][r] = -1e9f;
        }
    }
    float alpha[4];
#pragma unroll
    for (int r = 0; r < 4; r++) {
      float mx = fmaxf(fmaxf(sv[0][r], sv[1][r]), fmaxf(sv[2][r], sv[3][r]));
      for (int off = 1; off < 16; off <<= 1) mx = fmaxf(mx, __shfl_xor(mx, off));
      float mn = fmaxf(m_r[r], mx);
      float rs = 0.0f;
#pragma unroll
      for (int c = 0; c < 4; c++) {
        float p = fexp2(sv[c][r] - mn);
        sv[c][r] = p;
        rs += p;
      }
      for (int off = 1; off < 16; off <<= 1) rs += __shfl_xor(rs, off);
      alpha[r] = fexp2(m_r[r] - mn);
      l_r[r] = l_r[r] * alpha[r] + rs;
      m_r[r] = mn;
    }
#pragma unroll
    for (int c = 0; c < 4; c++)
#pragma unroll
      for (int r = 0; r < 4; r++) oacc[c][r] *= alpha[r];
    // C-layout -> A-layout via per-wave LDS slice (no barrier needed)
#pragma unroll
    for (int c = 0; c < 4; c++)
#pragma unroll
      for (int r = 0; r < 4; r++)
        pl[quad * 4 + r][c * 16 + ml] = f2b(sv[c][r]);
    bf8 pf[2];
#pragma unroll
    for (int kk = 0; kk < 2; kk++) pf[kk] = ld8(&pl[ml][kk * 32 + quad * 8]);
#pragma unroll
    for (int c = 0; c < 4; c++)
#pragma unroll
      for (int kk = 0; kk < 2; kk++)
        oacc[c] = MFMA(pf[kk], vf[c * 2 + kk], oacc[c]);
  }
#pragma unroll
  for (int c = 0; c < 4; c++)
#pragma unroll
    for (int r = 0; r < 4; r++) {
      int row = q0 + quad * 4 + r;
      obuf[(size_t)(b * SS + row) * DDIM + h * 64 + c * 16 + ml] =
          f2b(oacc[c][r] / l_r[r]);
    }
}

// ---------------- final: out = (y+ffn) + mhc ----------------
__global__ __launch_bounds__(256) void final_k(const float* __restrict__ yffn,
                                               const float* __restrict__ xd,
                                               const float* __restrict__ hres,
                                               const float* __restrict__ gres,
                                               float* __restrict__ out) {
  int row = blockIdx.x;  // [B*S]
  int b = row / SS;
  int tid = threadIdx.x;
  __shared__ float cf[8][8];
  if (tid < 64) cf[tid >> 3][tid & 7] = hres[tid] * gres[b * NSTR + (tid & 7)];
  __syncthreads();
  const float* yr = yffn + (size_t)row * DDIM;
  const float* xr = xd + (size_t)row * DDIM;
  float* o = out + (size_t)row * DDIM;
  for (int i = tid; i < DDIM; i += 256) {
    int m = i >> 7, dd = i & 127;
    float acc = yr[i];
#pragma unroll
    for (int n = 0; n < 8; n++) acc += cf[m][n] * xr[n * SDIMC + dd];
    o[i] = acc;
  }
}

extern "C" void kernel_launch(void* const* d_in, const int* in_sizes, int n_in,
                              void* d_out, int out_size, void* d_ws, size_t ws_size,
                              hipStream_t stream) {
  const float* x     = (const float*)d_in[0];
  const float* decay = (const float*)d_in[3];
  const float* gw    = (const float*)d_in[4];
  const float* gb    = (const float*)d_in[5];
  const float* phi   = (const float*)d_in[6];
  const float* ln1   = (const float*)d_in[7];
  const float* ln2   = (const float*)d_in[8];
  const float* w1    = (const float*)d_in[9];
  const float* b1    = (const float*)d_in[10];
  const float* w2    = (const float*)d_in[11];
  const float* b2    = (const float*)d_in[12];
  const float* ipw   = (const float*)d_in[13];
  const float* ipb   = (const float*)d_in[14];
  const float* ow    = (const float*)d_in[15];
  const float* obs   = (const float*)d_in[16];
  float* out = (float*)d_out;

  // ---- workspace layout (105 MB total) ----
  const size_t MB = 1048576ull;
  char* wsp = (char*)d_ws;
  float* SA   = (float*)(wsp);                 // 128 KB  chunk states / sums
  float* SIN  = (float*)(wsp + 131072ull);     // 128 KB  incoming states
  float* GRES = (float*)(wsp + 262144ull);     // 64 B
  float* HRES = (float*)(wsp + 262208ull);     // 256 B
  float* XD   = (float*)(wsp + 1 * MB);        // 16 MB   x_delta (f32)
  float* AO   = (float*)(wsp + 17 * MB);       // 16 MB   y; then y+ffn in-place
  bf16*  NORM = (bf16*)(wsp + 33 * MB);        // 8 MB    normed / normed2 (bf16)
  bf16*  OB   = (bf16*)(wsp + 41 * MB);        // 8 MB    attn heads out (bf16)
  bf16*  QKV  = (bf16*)(wsp + 49 * MB);        // 24 MB   (dead after flash)
  bf16*  VT   = (bf16*)(wsp + 73 * MB);        // 8 MB    (dead after flash)
  bf16*  HB   = (bf16*)(wsp + 49 * MB);        // 32 MB   gelu hidden, ALIASES QKV+VT
  float* FFN  = (float*)(wsp + 17 * MB);       // in-place over AO (same-thread RMW)
  bf16*  WIPW = (bf16*)(wsp + 81 * MB);        // 6 MB    in_proj_w bf16
  bf16*  WOW  = (bf16*)(wsp + 87 * MB);        // 2 MB    out_w bf16
  bf16*  W1B  = (bf16*)(wsp + 89 * MB);        // 8 MB    w1 bf16
  bf16*  W2B  = (bf16*)(wsp + 97 * MB);        // 8 MB    w2 bf16

  // 0: convert GEMM weights f32 -> bf16
  cvt_k<<<dim3((3 * DDIM * DDIM + 255) / 256), dim3(256), 0, stream>>>(ipw, WIPW, 3 * DDIM * DDIM);
  cvt_k<<<dim3((DDIM * DDIM + 255) / 256), dim3(256), 0, stream>>>(ow, WOW, DDIM * DDIM);
  cvt_k<<<dim3((4 * DDIM * DDIM + 255) / 256), dim3(256), 0, stream>>>(w1, W1B, 4 * DDIM * DDIM);
  cvt_k<<<dim3((4 * DDIM * DDIM + 255) / 256), dim3(256), 0, stream>>>(w2, W2B, 4 * DDIM * DDIM);

  // 1-3: delta operator scan
  delta_passA<<<dim3(BB * NCH * DDIM / 256), dim3(256), 0, stream>>>(x, decay, SA);
  delta_passB<<<dim3(BB * DDIM / 256), dim3(256), 0, stream>>>(SA, decay, SIN);
  delta_passC<<<dim3(BB * NCH * DDIM / 256), dim3(256), 0, stream>>>(x, decay, SIN, XD, SA);
  // 4: gates + sinkhorn
  gates_sinkhorn<<<dim3(1), dim3(1024), 0, stream>>>(SA, gw, gb, phi, GRES, HRES);
  // 5: rmsnorm1 (XD -> NORM)
  rmsnorm_k<<<dim3(BB * SS), dim3(256), 0, stream>>>(XD, ln1, NORM);
  // 6: qkv = NORM @ in_proj_w.T + in_proj_b   [4096 x 3072]
  gemm_lds<1, 0><<<dim3(32, 24), dim3(256), 0, stream>>>(NORM, WIPW, ipb, nullptr,
                                                         QKV, BB * SS, 3 * DDIM, DDIM);
  // 7: V transpose
  vtrans<<<dim3(BB * NHEAD * (SS / 64)), dim3(256), 0, stream>>>(QKV, VT);
  // 8: flash attention -> OB   (4 independent waves/block, balanced)
  flash_attn<<<dim3(BB * NHEAD * 32), dim3(256), 0, stream>>>(QKV, VT, OB);
  // 9: out-proj + residual(XD) -> AO  (BM=64 tile: 512 blocks = 2/CU)
  gemm_lds64<0, 2><<<dim3(64, 8), dim3(256), 0, stream>>>(OB, WOW, obs, XD,
                                                          AO, BB * SS, DDIM, DDIM);
  // 10: rmsnorm2 (AO -> NORM)
  rmsnorm_k<<<dim3(BB * SS), dim3(256), 0, stream>>>(AO, ln2, NORM);
  // 11: ffn1 + gelu -> HB   [4096 x 4096]  (HB aliases dead QKV/VT)
  gemm_lds<1, 1><<<dim3(32, 32), dim3(256), 0, stream>>>(NORM, W1B, b1, nullptr,
                                                         HB, BB * SS, 4 * DDIM, DDIM);
  // 12: ffn2 + residual(AO=y) -> FFN (in-place over AO; same-thread RMW)
  gemm_lds64<0, 2><<<dim3(64, 8), dim3(256), 0, stream>>>(HB, W2B, b2, AO,
                                                          FFN, BB * SS, DDIM, 4 * DDIM);
  // 13: final out = FFN + mhc(XD)
  final_k<<<dim3(BB * SS), dim3(256), 0, stream>>>(FFN, XD, HRES, GRES, out);
}

// Round 7
// 538.817 us; speedup vs baseline: 2.6806x; 1.2099x over previous
//
#include <hip/hip_runtime.h>
#include <hip/hip_bf16.h>
#include <math.h>

// Problem constants
#define BB 2
#define SS 2048
#define DDIM 1024
#define NHEAD 16
#define NSTR 8
#define SDIMC 128
#define NCH 16      // chunks for delta scan
#define CLEN 128    // chunk length
#define EPSV 1e-6f

using bf16 = __hip_bfloat16;
typedef __attribute__((ext_vector_type(8))) __bf16 bf8;
typedef __attribute__((ext_vector_type(4))) float f4;

__device__ __forceinline__ bf16 f2b(float v) { return __float2bfloat16(v); }
__device__ __forceinline__ bf8 ld8(const bf16* p) { return *(const bf8*)p; }
__device__ __forceinline__ f4 MFMA(bf8 a, bf8 b, f4 c) {
  return __builtin_amdgcn_mfma_f32_16x16x32_bf16(a, b, c, 0, 0, 0);
}
__device__ __forceinline__ float sigm(float x) { return 1.0f / (1.0f + expf(-x)); }
__device__ __forceinline__ float fexp2(float x) { return __builtin_amdgcn_exp2f(x); }

// async global->LDS 16B copy (m97 pattern; LDS dest must be uniform + lane*16)
__device__ __forceinline__ void glds16(bf16* l, const bf16* g) {
  __builtin_amdgcn_global_load_lds(
      (const __attribute__((address_space(1))) unsigned int*)g,
      (__attribute__((address_space(3))) unsigned int*)l, 16, 0, 0);
}

// ---------------- f32 -> bf16 weight conversion ----------------
__global__ __launch_bounds__(256) void cvt_k(const float* __restrict__ in,
                                             bf16* __restrict__ out, int n) {
  int i = blockIdx.x * 256 + threadIdx.x;
  if (i < n) out[i] = f2b(in[i]);
}

// ---------------- Delta operator: 3-pass chunked affine scan ----------------
__global__ __launch_bounds__(256) void delta_passA(const float* __restrict__ x,
                                                   const float* __restrict__ decay,
                                                   float* __restrict__ SA) {
  int idx = blockIdx.x * 256 + threadIdx.x;      // [b][c][d]
  int d = idx % DDIM;
  int c = (idx / DDIM) % NCH;
  int b = idx / (DDIM * NCH);
  float beta = sigm(decay[d]);
  float omb = 1.0f - beta;
  const float* xp = x + ((size_t)(b * SS + c * CLEN)) * DDIM + d;
  float s = 0.0f;
  for (int j = 0; j < CLEN; j++) {
    float xv = xp[(size_t)j * DDIM];
    s = beta * s + omb * xv;
  }
  SA[idx] = s;
}

__global__ __launch_bounds__(256) void delta_passB(const float* __restrict__ SA,
                                                   const float* __restrict__ decay,
                                                   float* __restrict__ SIN) {
  int idx = blockIdx.x * 256 + threadIdx.x;      // [b][d]
  int d = idx % DDIM;
  int b = idx / DDIM;
  float beta = sigm(decay[d]);
  float p = beta;
  for (int i = 0; i < 7; i++) p *= p;            // beta^128
  float s = 0.0f;
  for (int c = 0; c < NCH; c++) {
    SIN[(b * NCH + c) * DDIM + d] = s;
    s = p * s + SA[(b * NCH + c) * DDIM + d];
  }
}

__global__ __launch_bounds__(256) void delta_passC(const float* __restrict__ x,
                                                   const float* __restrict__ decay,
                                                   const float* __restrict__ SIN,
                                                   float* __restrict__ XD,
                                                   float* __restrict__ SA) {
  int idx = blockIdx.x * 256 + threadIdx.x;      // [b][c][d]
  int d = idx % DDIM;
  int c = (idx / DDIM) % NCH;
  int b = idx / (DDIM * NCH);
  float beta = sigm(decay[d]);
  float omb = 1.0f - beta;
  const float* xp = x + ((size_t)(b * SS + c * CLEN)) * DDIM + d;
  float* xdp = XD + ((size_t)(b * SS + c * CLEN)) * DDIM + d;
  float s = SIN[idx];
  float sum = 0.0f;
  for (int j = 0; j < CLEN; j++) {
    float xv = xp[(size_t)j * DDIM];
    float o = xv - s;
    xdp[(size_t)j * DDIM] = o;
    sum += o;
    s = beta * s + omb * xv;
  }
  SA[idx] = sum;
}

// ---------------- gates (g_res) + sinkhorn ----------------
__global__ __launch_bounds__(1024) void gates_sinkhorn(const float* __restrict__ SA,
                                                       const float* __restrict__ gw,
                                                       const float* __restrict__ gb,
                                                       const float* __restrict__ phi,
                                                       float* __restrict__ gres,
                                                       float* __restrict__ hres) {
  int tid = threadIdx.x;
  int wave = tid >> 6, lane = tid & 63;
  int b = wave >> 3, j = wave & 7;               // 16 waves: (b, gate j)
  float acc = 0.0f;
  for (int d = lane; d < DDIM; d += 64) {
    float xs = 0.0f;
    for (int c = 0; c < NCH; c++) xs += SA[(b * NCH + c) * DDIM + d];
    xs *= (1.0f / (float)SS);
    acc += xs * gw[(2 * NSTR + j) * DDIM + d];
  }
  for (int off = 32; off > 0; off >>= 1) acc += __shfl_down(acc, off);
  if (lane == 0) gres[b * NSTR + j] = sigm(acc + gb[2 * NSTR + j]);
  __syncthreads();
  if (tid == 0) {
    float Km[8][8];
    for (int i = 0; i < 8; i++)
      for (int jj = 0; jj < 8; jj++) Km[i][jj] = expf(phi[i * 8 + jj]);
    for (int it = 0; it < 15; it++) {
      for (int i = 0; i < 8; i++) {
        float rs = 0.0f;
        for (int jj = 0; jj < 8; jj++) rs += Km[i][jj];
        float inv = 1.0f / rs;
        for (int jj = 0; jj < 8; jj++) Km[i][jj] *= inv;
      }
      for (int jj = 0; jj < 8; jj++) {
        float cs = 0.0f;
        for (int i = 0; i < 8; i++) cs += Km[i][jj];
        float inv = 1.0f / cs;
        for (int i = 0; i < 8; i++) Km[i][jj] *= inv;
      }
    }
    for (int i = 0; i < 8; i++)
      for (int jj = 0; jj < 8; jj++) hres[i * 8 + jj] = Km[i][jj];
  }
}

// ---------------- RMSNorm (f32 in -> bf16 out) ----------------
__global__ __launch_bounds__(256) void rmsnorm_k(const float* __restrict__ in,
                                                 const float* __restrict__ w,
                                                 bf16* __restrict__ out) {
  int row = blockIdx.x;
  const float* r = in + (size_t)row * DDIM;
  int tid = threadIdx.x;
  float ss = 0.0f;
  for (int i = tid; i < DDIM; i += 256) {
    float v = r[i];
    ss += v * v;
  }
  for (int off = 32; off > 0; off >>= 1) ss += __shfl_down(ss, off);
  __shared__ float red[4];
  if ((tid & 63) == 0) red[tid >> 6] = ss;
  __syncthreads();
  float tot = red[0] + red[1] + red[2] + red[3];
  float sc = rsqrtf(tot / (float)DDIM + EPSV);
  bf16* o = out + (size_t)row * DDIM;
  for (int i = tid; i < DDIM; i += 256) o[i] = f2b(r[i] * sc * w[i]);
}

// ------- MFMA GEMM, m97 structure: 128x128 tile, BK=32, global_load_lds -----
// ODT: 0=f32 out, 1=bf16 out.  EPI: 0=none, 1=gelu(exact erf), 2=add residual
template <int ODT, int EPI>
__global__ __launch_bounds__(256) void gemm_lds(const bf16* __restrict__ A,
                                                const bf16* __restrict__ W,
                                                const float* __restrict__ bias,
                                                const float* __restrict__ res,
                                                void* __restrict__ outp,
                                                int M, int N, int K) {
  __shared__ bf16 As[128 * 32];
  __shared__ bf16 Bs[128 * 32];
  int tid = threadIdx.x;
  int lane = tid & 63, wv = tid >> 6;
  int ml = lane & 15, quad = lane >> 4;
  int wr = wv >> 1, wc = wv & 1;
  int m0 = blockIdx.x * 128, n0 = blockIdx.y * 128;
  f4 acc[4][4] = {};
  for (int k0 = 0; k0 < K; k0 += 32) {
#pragma unroll
    for (int it = 0; it < 2; it++) {
      int c = it * 256 + tid;             // 512 16B-chunks per tile
      int row = c >> 2, kc = (c & 3) * 8;
      glds16(&As[c * 8], A + (size_t)(m0 + row) * K + k0 + kc);
      glds16(&Bs[c * 8], W + (size_t)(n0 + row) * K + k0 + kc);
    }
    __syncthreads();
    bf8 af[4], bfr[4];
#pragma unroll
    for (int mi = 0; mi < 4; mi++)
      af[mi] = ld8(&As[(wr * 64 + mi * 16 + ml) * 32 + quad * 8]);
#pragma unroll
    for (int ni = 0; ni < 4; ni++)
      bfr[ni] = ld8(&Bs[(wc * 64 + ni * 16 + ml) * 32 + quad * 8]);
#pragma unroll
    for (int mi = 0; mi < 4; mi++)
#pragma unroll
      for (int ni = 0; ni < 4; ni++)
        acc[mi][ni] = MFMA(af[mi], bfr[ni], acc[mi][ni]);
    __syncthreads();
  }
#pragma unroll
  for (int mi = 0; mi < 4; mi++)
#pragma unroll
    for (int ni = 0; ni < 4; ni++)
#pragma unroll
      for (int r = 0; r < 4; r++) {
        int row = m0 + wr * 64 + mi * 16 + quad * 4 + r;
        int col = n0 + wc * 64 + ni * 16 + ml;
        size_t idx = (size_t)row * N + col;
        float v = acc[mi][ni][r] + bias[col];
        if (EPI == 1) v = 0.5f * v * (1.0f + erff(v * 0.70710678118654752f));
        if (EPI == 2) v += res[idx];
        if (ODT == 1) ((bf16*)outp)[idx] = f2b(v);
        else ((float*)outp)[idx] = v;
      }
}

// ------- MFMA GEMM, BM=64 x BN=128 variant (2 blocks/CU for N=1024 GEMMs) ---
template <int ODT, int EPI>
__global__ __launch_bounds__(256) void gemm_lds64(const bf16* __restrict__ A,
                                                  const bf16* __restrict__ W,
                                                  const float* __restrict__ bias,
                                                  const float* __restrict__ res,
                                                  void* __restrict__ outp,
                                                  int M, int N, int K) {
  __shared__ bf16 As[64 * 32];
  __shared__ bf16 Bs[128 * 32];
  int tid = threadIdx.x;
  int lane = tid & 63, wv = tid >> 6;
  int ml = lane & 15, quad = lane >> 4;
  int wr = wv & 1, wc = wv >> 1;        // wave tile: 32 rows x 64 cols
  int m0 = blockIdx.x * 64, n0 = blockIdx.y * 128;
  f4 acc[2][4] = {};
  for (int k0 = 0; k0 < K; k0 += 32) {
    {
      int c = tid;                      // A: 256 chunks
      int row = c >> 2, kc = (c & 3) * 8;
      glds16(&As[c * 8], A + (size_t)(m0 + row) * K + k0 + kc);
    }
#pragma unroll
    for (int it = 0; it < 2; it++) {    // B: 512 chunks
      int c = it * 256 + tid;
      int row = c >> 2, kc = (c & 3) * 8;
      glds16(&Bs[c * 8], W + (size_t)(n0 + row) * K + k0 + kc);
    }
    __syncthreads();
    bf8 af[2], bfr[4];
#pragma unroll
    for (int mi = 0; mi < 2; mi++)
      af[mi] = ld8(&As[(wr * 32 + mi * 16 + ml) * 32 + quad * 8]);
#pragma unroll
    for (int ni = 0; ni < 4; ni++)
      bfr[ni] = ld8(&Bs[(wc * 64 + ni * 16 + ml) * 32 + quad * 8]);
#pragma unroll
    for (int mi = 0; mi < 2; mi++)
#pragma unroll
      for (int ni = 0; ni < 4; ni++)
        acc[mi][ni] = MFMA(af[mi], bfr[ni], acc[mi][ni]);
    __syncthreads();
  }
#pragma unroll
  for (int mi = 0; mi < 2; mi++)
#pragma unroll
    for (int ni = 0; ni < 4; ni++)
#pragma unroll
      for (int r = 0; r < 4; r++) {
        int row = m0 + wr * 32 + mi * 16 + quad * 4 + r;
        int col = n0 + wc * 64 + ni * 16 + ml;
        size_t idx = (size_t)row * N + col;
        float v = acc[mi][ni][r] + bias[col];
        if (EPI == 1) v = 0.5f * v * (1.0f + erff(v * 0.70710678118654752f));
        if (EPI == 2) v += res[idx];
        if (ODT == 1) ((bf16*)outp)[idx] = f2b(v);
        else ((float*)outp)[idx] = v;
      }
}

// ---------------- V transpose: VT[b,h,d,s] = qkv[b,s,2D + h*64 + d] --------
__global__ __launch_bounds__(256) void vtrans(const bf16* __restrict__ qkv,
                                              bf16* __restrict__ VT) {
  int bid = blockIdx.x;
  int st = bid % (SS / 64);
  int h = (bid / (SS / 64)) % NHEAD;
  int b = bid / ((SS / 64) * NHEAD);
  __shared__ bf16 tile[64][65];
  int s0 = st * 64;
  int tid = threadIdx.x;
  for (int it = 0; it < 16; it++) {
    int sl = it * 4 + (tid >> 6), dl = tid & 63;
    tile[sl][dl] = qkv[(size_t)(b * SS + s0 + sl) * (3 * DDIM) + 2 * DDIM + h * 64 + dl];
  }
  __syncthreads();
  for (int it = 0; it < 16; it++) {
    int dl = it * 4 + (tid >> 6), sl = tid & 63;
    VT[((size_t)(b * NHEAD + h) * 64 + dl) * SS + s0 + sl] = tile[sl][dl];
  }
}

// ---- Flash attention v3: antithetic pairing + K/V register double-buffer ---
// One wave processes Q-subtiles idx and 127-idx: total KV-tiles = 33 for
// EVERY wave -> exact balance independent of dispatch mapping. 512 uniform
// blocks. K/V of tile kt+1 prefetched into registers while computing kt.
__device__ __forceinline__ void loadK(bf8* dst, const bf16* kbase, int k0,
                                      int ml, int quad) {
#pragma unroll
  for (int kk = 0; kk < 2; kk++)
#pragma unroll
    for (int c = 0; c < 4; c++)
      dst[kk * 4 + c] =
          ld8(kbase + (size_t)(k0 + c * 16 + ml) * (3 * DDIM) + kk * 32 + quad * 8);
}
__device__ __forceinline__ void loadV(bf8* dst, const bf16* vbase, int k0,
                                      int ml, int quad) {
#pragma unroll
  for (int c = 0; c < 4; c++)
#pragma unroll
    for (int kk = 0; kk < 2; kk++)
      dst[c * 2 + kk] =
          ld8(vbase + (size_t)(c * 16 + ml) * SS + k0 + kk * 32 + quad * 8);
}

__device__ __forceinline__ void attend16(const bf16* __restrict__ qkv,
                                         const bf16* __restrict__ kbase,
                                         const bf16* __restrict__ vbase,
                                         bf16* __restrict__ obuf,
                                         int b, int h, int q0,
                                         int ml, int quad, bf16 (*pl)[64]) {
  const float SC = 0.125f * 1.44269504089f;   // 1/sqrt(64) * log2(e)
  bf8 qf[2];
#pragma unroll
  for (int kk = 0; kk < 2; kk++)
    qf[kk] = ld8(qkv + (size_t)(b * SS + q0 + ml) * (3 * DDIM) + h * 64 + kk * 32 + quad * 8);

  f4 oacc[4] = {{0,0,0,0},{0,0,0,0},{0,0,0,0},{0,0,0,0}};
  float m_r[4], l_r[4];
#pragma unroll
  for (int r = 0; r < 4; r++) { m_r[r] = -1e30f; l_r[r] = 0.0f; }

  int nkt = (q0 >> 6) + 1;
  bf8 kc[8], vc[8], kn[8], vn[8];
  loadK(kc, kbase, 0, ml, quad);
  loadV(vc, vbase, 0, ml, quad);
  for (int kt = 0; kt < nkt; kt++) {
    int ktn = (kt + 1 < nkt) ? kt + 1 : kt;   // clamped prefetch (straight-line)
    loadK(kn, kbase, ktn * 64, ml, quad);
    loadV(vn, vbase, ktn * 64, ml, quad);
    int k0 = kt * 64;
    f4 sacc[4] = {{0,0,0,0},{0,0,0,0},{0,0,0,0},{0,0,0,0}};
#pragma unroll
    for (int kk = 0; kk < 2; kk++)
#pragma unroll
      for (int c = 0; c < 4; c++)
        sacc[c] = MFMA(qf[kk], kc[kk * 4 + c], sacc[c]);
    float sv[4][4];
#pragma unroll
    for (int c = 0; c < 4; c++)
#pragma unroll
      for (int r = 0; r < 4; r++) sv[c][r] = sacc[c][r] * SC;
    if (kt == nkt - 1) {                // only the diagonal tile needs masking
#pragma unroll
      for (int c = 0; c < 4; c++)
#pragma unroll
        for (int r = 0; r < 4; r++) {
          int qi = q0 + quad * 4 + r;
          int kj = k0 + c * 16 + ml;
          if (kj > qi) sv[c][r] = -1e9f;
        }
    }
    float alpha[4];
#pragma unroll
    for (int r = 0; r < 4; r++) {
      float mx = fmaxf(fmaxf(sv[0][r], sv[1][r]), fmaxf(sv[2][r], sv[3][r]));
#pragma unroll
      for (int off = 1; off < 16; off <<= 1) mx = fmaxf(mx, __shfl_xor(mx, off));
      float mn = fmaxf(m_r[r], mx);
      float rs = 0.0f;
#pragma unroll
      for (int c = 0; c < 4; c++) {
        float p = fexp2(sv[c][r] - mn);
        sv[c][r] = p;
        rs += p;
      }
#pragma unroll
      for (int off = 1; off < 16; off <<= 1) rs += __shfl_xor(rs, off);
      alpha[r] = fexp2(m_r[r] - mn);
      l_r[r] = l_r[r] * alpha[r] + rs;
      m_r[r] = mn;
    }
#pragma unroll
    for (int c = 0; c < 4; c++)
#pragma unroll
      for (int r = 0; r < 4; r++) oacc[c][r] *= alpha[r];
    // C-layout -> A-layout via per-wave LDS slice (no barrier needed)
#pragma unroll
    for (int c = 0; c < 4; c++)
#pragma unroll
      for (int r = 0; r < 4; r++)
        pl[quad * 4 + r][c * 16 + ml] = f2b(sv[c][r]);
    bf8 pf[2];
#pragma unroll
    for (int kk = 0; kk < 2; kk++) pf[kk] = ld8(&pl[ml][kk * 32 + quad * 8]);
#pragma unroll
    for (int c = 0; c < 4; c++)
#pragma unroll
      for (int kk = 0; kk < 2; kk++)
        oacc[c] = MFMA(pf[kk], vc[c * 2 + kk], oacc[c]);
#pragma unroll
    for (int i = 0; i < 8; i++) { kc[i] = kn[i]; vc[i] = vn[i]; }
  }
#pragma unroll
  for (int c = 0; c < 4; c++)
#pragma unroll
    for (int r = 0; r < 4; r++) {
      int row = q0 + quad * 4 + r;
      obuf[(size_t)(b * SS + row) * DDIM + h * 64 + c * 16 + ml] =
          f2b(oacc[c][r] / l_r[r]);
    }
}

__global__ __launch_bounds__(256, 2) void flash_attn(const bf16* __restrict__ qkv,
                                                     const bf16* __restrict__ VT,
                                                     bf16* __restrict__ obuf) {
  int bid = blockIdx.x;                 // grid: BB*NHEAD*16 = 512 uniform blocks
  int blk = bid & 15;
  int h = (bid >> 4) & 15;
  int b = bid >> 8;
  int wv = threadIdx.x >> 6, lane = threadIdx.x & 63;
  int ml = lane & 15, quad = lane >> 4;
  int idx = blk * 4 + wv;               // 0..63

  __shared__ __align__(16) bf16 plds[4][16][64];
  bf16 (*pl)[64] = plds[wv];            // per-wave private slice

  const bf16* kbase = qkv + (size_t)b * SS * (3 * DDIM) + DDIM + h * 64;
  const bf16* vbase = VT + (size_t)(b * NHEAD + h) * 64 * SS;

  attend16(qkv, kbase, vbase, obuf, b, h, idx * 16, ml, quad, pl);
  attend16(qkv, kbase, vbase, obuf, b, h, (127 - idx) * 16, ml, quad, pl);
}

// ---------------- final: out = (y+ffn) + mhc ----------------
__global__ __launch_bounds__(256) void final_k(const float* __restrict__ yffn,
                                               const float* __restrict__ xd,
                                               const float* __restrict__ hres,
                                               const float* __restrict__ gres,
                                               float* __restrict__ out) {
  int row = blockIdx.x;  // [B*S]
  int b = row / SS;
  int tid = threadIdx.x;
  __shared__ float cf[8][8];
  if (tid < 64) cf[tid >> 3][tid & 7] = hres[tid] * gres[b * NSTR + (tid & 7)];
  __syncthreads();
  const float* yr = yffn + (size_t)row * DDIM;
  const float* xr = xd + (size_t)row * DDIM;
  float* o = out + (size_t)row * DDIM;
  for (int i = tid; i < DDIM; i += 256) {
    int m = i >> 7, dd = i & 127;
    float acc = yr[i];
#pragma unroll
    for (int n = 0; n < 8; n++) acc += cf[m][n] * xr[n * SDIMC + dd];
    o[i] = acc;
  }
}

extern "C" void kernel_launch(void* const* d_in, const int* in_sizes, int n_in,
                              void* d_out, int out_size, void* d_ws, size_t ws_size,
                              hipStream_t stream) {
  const float* x     = (const float*)d_in[0];
  const float* decay = (const float*)d_in[3];
  const float* gw    = (const float*)d_in[4];
  const float* gb    = (const float*)d_in[5];
  const float* phi   = (const float*)d_in[6];
  const float* ln1   = (const float*)d_in[7];
  const float* ln2   = (const float*)d_in[8];
  const float* w1    = (const float*)d_in[9];
  const float* b1    = (const float*)d_in[10];
  const float* w2    = (const float*)d_in[11];
  const float* b2    = (const float*)d_in[12];
  const float* ipw   = (const float*)d_in[13];
  const float* ipb   = (const float*)d_in[14];
  const float* ow    = (const float*)d_in[15];
  const float* obs   = (const float*)d_in[16];
  float* out = (float*)d_out;

  // ---- workspace layout (105 MB total) ----
  const size_t MB = 1048576ull;
  char* wsp = (char*)d_ws;
  float* SA   = (float*)(wsp);                 // 128 KB  chunk states / sums
  float* SIN  = (float*)(wsp + 131072ull);     // 128 KB  incoming states
  float* GRES = (float*)(wsp + 262144ull);     // 64 B
  float* HRES = (float*)(wsp + 262208ull);     // 256 B
  float* XD   = (float*)(wsp + 1 * MB);        // 16 MB   x_delta (f32)
  float* AO   = (float*)(wsp + 17 * MB);       // 16 MB   y; then y+ffn in-place
  bf16*  NORM = (bf16*)(wsp + 33 * MB);        // 8 MB    normed / normed2 (bf16)
  bf16*  OB   = (bf16*)(wsp + 41 * MB);        // 8 MB    attn heads out (bf16)
  bf16*  QKV  = (bf16*)(wsp + 49 * MB);        // 24 MB   (dead after flash)
  bf16*  VT   = (bf16*)(wsp + 73 * MB);        // 8 MB    (dead after flash)
  bf16*  HB   = (bf16*)(wsp + 49 * MB);        // 32 MB   gelu hidden, ALIASES QKV+VT
  float* FFN  = (float*)(wsp + 17 * MB);       // in-place over AO (same-thread RMW)
  bf16*  WIPW = (bf16*)(wsp + 81 * MB);        // 6 MB    in_proj_w bf16
  bf16*  WOW  = (bf16*)(wsp + 87 * MB);        // 2 MB    out_w bf16
  bf16*  W1B  = (bf16*)(wsp + 89 * MB);        // 8 MB    w1 bf16
  bf16*  W2B  = (bf16*)(wsp + 97 * MB);        // 8 MB    w2 bf16

  // 0: convert GEMM weights f32 -> bf16
  cvt_k<<<dim3((3 * DDIM * DDIM + 255) / 256), dim3(256), 0, stream>>>(ipw, WIPW, 3 * DDIM * DDIM);
  cvt_k<<<dim3((DDIM * DDIM + 255) / 256), dim3(256), 0, stream>>>(ow, WOW, DDIM * DDIM);
  cvt_k<<<dim3((4 * DDIM * DDIM + 255) / 256), dim3(256), 0, stream>>>(w1, W1B, 4 * DDIM * DDIM);
  cvt_k<<<dim3((4 * DDIM * DDIM + 255) / 256), dim3(256), 0, stream>>>(w2, W2B, 4 * DDIM * DDIM);

  // 1-3: delta operator scan
  delta_passA<<<dim3(BB * NCH * DDIM / 256), dim3(256), 0, stream>>>(x, decay, SA);
  delta_passB<<<dim3(BB * DDIM / 256), dim3(256), 0, stream>>>(SA, decay, SIN);
  delta_passC<<<dim3(BB * NCH * DDIM / 256), dim3(256), 0, stream>>>(x, decay, SIN, XD, SA);
  // 4: gates + sinkhorn
  gates_sinkhorn<<<dim3(1), dim3(1024), 0, stream>>>(SA, gw, gb, phi, GRES, HRES);
  // 5: rmsnorm1 (XD -> NORM)
  rmsnorm_k<<<dim3(BB * SS), dim3(256), 0, stream>>>(XD, ln1, NORM);
  // 6: qkv = NORM @ in_proj_w.T + in_proj_b   [4096 x 3072]
  gemm_lds<1, 0><<<dim3(32, 24), dim3(256), 0, stream>>>(NORM, WIPW, ipb, nullptr,
                                                         QKV, BB * SS, 3 * DDIM, DDIM);
  // 7: V transpose
  vtrans<<<dim3(BB * NHEAD * (SS / 64)), dim3(256), 0, stream>>>(QKV, VT);
  // 8: flash attention -> OB  (512 uniform blocks, antithetic pairing)
  flash_attn<<<dim3(BB * NHEAD * 16), dim3(256), 0, stream>>>(QKV, VT, OB);
  // 9: out-proj + residual(XD) -> AO  (BM=64 tile: 512 blocks = 2/CU)
  gemm_lds64<0, 2><<<dim3(64, 8), dim3(256), 0, stream>>>(OB, WOW, obs, XD,
                                                          AO, BB * SS, DDIM, DDIM);
  // 10: rmsnorm2 (AO -> NORM)
  rmsnorm_k<<<dim3(BB * SS), dim3(256), 0, stream>>>(AO, ln2, NORM);
  // 11: ffn1 + gelu -> HB   [4096 x 4096]  (HB aliases dead QKV/VT)
  gemm_lds<1, 1><<<dim3(32, 32), dim3(256), 0, stream>>>(NORM, W1B, b1, nullptr,
                                                         HB, BB * SS, 4 * DDIM, DDIM);
  // 12: ffn2 + residual(AO=y) -> FFN (in-place over AO; same-thread RMW)
  gemm_lds64<0, 2><<<dim3(64, 8), dim3(256), 0, stream>>>(HB, W2B, b2, AO,
                                                          FFN, BB * SS, DDIM, 4 * DDIM);
  // 13: final out = FFN + mhc(XD)
  final_k<<<dim3(BB * SS), dim3(256), 0, stream>>>(FFN, XD, HRES, GRES, out);
}